// Round 7
// baseline (119.722 us; speedup 1.0000x reference)
//
#include <hip/hip_runtime.h>

// Pool_layer: B=4, N=8192, C=256, NEIGHBOR_NUM=4, P=N/4=2048
// d_out = vertices_pool (B,P,3) fp32 || feature_map_pool (B,P,C) fp32.
//
// Reference: neighbors of query n = the 4 SMALLEST indices m with
// dist2(n,m) <= r^2 (self forced via zeroed diagonal), padded with the first
// hit. dist2 in the reference's exact fp32 order (FMA contraction blocked).
//
// R6 -> R7 (discriminating experiment): 256 blocks (1/CU). Each block stages
// the first 5120 candidates' xyz (60 KB, < 64 KB static-LDS limit) into LDS
// once with fully-coalesced float4 loads; each of its 4 waves serves 8
// queries ENTIRELY from LDS: lane-parallel per-lane-first-4 (ascending by
// construction) + 4-round shfl-min merge, early-exit every 1024 candidates.
// Only queries with <4 hits among the first 5120 (far-tail, ~0.1%) scan the
// remaining 3072 candidates from global. No per-wave global candidate
// traffic, different grid and epilogue shape from R2/R5/R6 — if the bench
// doesn't move, the residual is harness floor, not kernel.

#define BB 4
#define NN 8192
#define CC 256
#define PP 2048
#define KK 4
#define SS 5120               // candidates staged in LDS (60 KB)
#define NF4 (SS * 3 / 4)      // 3840 float4 in the stage
#define QPW 8                 // queries per wave (4 waves -> 32 queries/block)
#define CH2 16                // tail scan: 1024 candidates per round

__device__ __forceinline__ float dist_ref(float xn0, float xn1, float xn2, float sqn,
                                          float x0, float x1, float x2) {
    // sq_m = ((x*x)+(y*y))+(z*z); dot likewise; dist = (-2*dot)+sq_n+sq_m
    const float sqm = __fadd_rn(__fadd_rn(__fmul_rn(x0, x0), __fmul_rn(x1, x1)),
                                __fmul_rn(x2, x2));
    const float dot = __fadd_rn(__fadd_rn(__fmul_rn(xn0, x0), __fmul_rn(xn1, x1)),
                                __fmul_rn(xn2, x2));
    return __fadd_rn(__fadd_rn(__fmul_rn(-2.0f, dot), sqn), sqm);
}

__global__ __launch_bounds__(256) void pool_layer_kernel(
    const float* __restrict__ vertices,   // (B, N, 3)
    const float* __restrict__ feat,       // (B, N, C)
    const int*   __restrict__ radius_p,   // (1,)
    const int*   __restrict__ sample_idx, // (P,)
    float* __restrict__ out_v,            // (B, P, 3)
    float* __restrict__ out_f)            // (B, P, C)
{
    __shared__ float s_v[SS * 3];         // 60 KB

    const int tid  = threadIdx.x;
    const int wave = tid >> 6;
    const int lane = tid & 63;
    // block handles 32 consecutive queries; all share the same batch b
    const int q0 = blockIdx.x * 32;
    const int b  = q0 >> 11;              // q / P
    const float* vb = vertices + (size_t)b * NN * 3;

    // ---- cooperative staging: 3840 float4, 15/thread, coalesced ----
    const float4* v4 = (const float4*)vb;
    float4 st[15];
    #pragma unroll
    for (int k = 0; k < 15; ++k) st[k] = v4[tid + k * 256];
    #pragma unroll
    for (int k = 0; k < 15; ++k) ((float4*)s_v)[tid + k * 256] = st[k];

    const int   r  = radius_p[0];
    const float r2 = (float)(r * r);
    __syncthreads();

    for (int j = 0; j < QPW; ++j) {
        const int q = q0 + wave * QPW + j;
        const int i = q & (PP - 1);
        const int n = sample_idx[i];
        // wave-uniform query point (broadcast loads, 1 line each)
        const float xn0 = vb[n * 3 + 0];
        const float xn1 = vb[n * 3 + 1];
        const float xn2 = vb[n * 3 + 2];
        const float sqn = __fadd_rn(__fadd_rn(__fmul_rn(xn0, xn0), __fmul_rn(xn1, xn1)),
                                    __fmul_rn(xn2, xn2));
        if (lane < 3) out_v[((size_t)b * PP + i) * 3 + lane] = vb[n * 3 + lane];

        // ---- LDS scan: lane-parallel first-4, early exit per 1024 ----
        int l0 = NN, l1 = NN, l2 = NN, l3 = NN, lcnt = 0;
        int tot = 0;  // wave-uniform total hits in scanned prefix
        for (int base = 0; base < SS && tot < KK; base += 1024) {
            #pragma unroll
            for (int c = 0; c < 16; ++c) {
                const int m = base + c * 64 + lane;
                const float x0 = s_v[m * 3 + 0];
                const float x1 = s_v[m * 3 + 1];
                const float x2 = s_v[m * 3 + 2];
                const float dist = dist_ref(xn0, xn1, xn2, sqn, x0, x1, x2);
                const bool hit = (m == n) || !(dist > r2);
                tot += (int)__popcll(__ballot(hit));
                if (hit && lcnt < KK) {       // per-lane ascending first-4
                    l3 = (lcnt == 3) ? m : l3;
                    l2 = (lcnt == 2) ? m : l2;
                    l1 = (lcnt == 1) ? m : l1;
                    l0 = (lcnt == 0) ? m : l0;
                    ++lcnt;
                }
            }
        }

        // ---- rare tail: candidates SS..NN-1 from global ----
        if (tot < KK) {
            for (int base = SS; base < NN && tot < KK; base += 64 * CH2) {
                float qx[CH2], qy[CH2], qz[CH2];
                #pragma unroll
                for (int c = 0; c < CH2; ++c) {
                    const int m = base + c * 64 + lane;
                    qx[c] = vb[m * 3 + 0];
                    qy[c] = vb[m * 3 + 1];
                    qz[c] = vb[m * 3 + 2];
                }
                #pragma unroll
                for (int c = 0; c < CH2; ++c) {
                    const int m = base + c * 64 + lane;
                    const float dist = dist_ref(xn0, xn1, xn2, sqn, qx[c], qy[c], qz[c]);
                    const bool hit = (m == n) || !(dist > r2);
                    tot += (int)__popcll(__ballot(hit));
                    if (hit && lcnt < KK) {
                        l3 = (lcnt == 3) ? m : l3;
                        l2 = (lcnt == 2) ? m : l2;
                        l1 = (lcnt == 1) ? m : l1;
                        l0 = (lcnt == 0) ? m : l0;
                        ++lcnt;
                    }
                }
            }
        }

        // ---- k-way merge: 4 rounds of min-of-heads + pop-on-match ----
        int g[KK];
        #pragma unroll
        for (int round = 0; round < KK; ++round) {
            int mmin = l0;
            #pragma unroll
            for (int off = 32; off > 0; off >>= 1)
                mmin = min(mmin, __shfl_xor(mmin, off));
            g[round] = mmin;                  // wave-uniform
            if (l0 == mmin) { l0 = l1; l1 = l2; l2 = l3; l3 = NN; }
        }
        const int c0 = g[0];                  // self-hit guarantees validity
        const int c1 = (g[1] == NN) ? g[0] : g[1];
        const int c2 = (g[2] == NN) ? g[0] : g[2];
        const int c3 = (g[3] == NN) ? g[0] : g[3];

        // ---- max-pool 4 feature rows (64 lanes x float4 = 1 KB row) ----
        const float4 a0 = ((const float4*)(feat + ((size_t)b * NN + c0) * CC))[lane];
        const float4 a1 = ((const float4*)(feat + ((size_t)b * NN + c1) * CC))[lane];
        const float4 a2 = ((const float4*)(feat + ((size_t)b * NN + c2) * CC))[lane];
        const float4 a3 = ((const float4*)(feat + ((size_t)b * NN + c3) * CC))[lane];
        float4 o;
        o.x = fmaxf(fmaxf(a0.x, a1.x), fmaxf(a2.x, a3.x));
        o.y = fmaxf(fmaxf(a0.y, a1.y), fmaxf(a2.y, a3.y));
        o.z = fmaxf(fmaxf(a0.z, a1.z), fmaxf(a2.z, a3.z));
        o.w = fmaxf(fmaxf(a0.w, a1.w), fmaxf(a2.w, a3.w));
        ((float4*)(out_f + ((size_t)b * PP + i) * CC))[lane] = o;
    }
}

extern "C" void kernel_launch(void* const* d_in, const int* in_sizes, int n_in,
                              void* d_out, int out_size, void* d_ws, size_t ws_size,
                              hipStream_t stream) {
    const float* vertices   = (const float*)d_in[0]; // (B,N,3) fp32
    const float* feat       = (const float*)d_in[1]; // (B,N,C) fp32
    const int*   radius_p   = (const int*)d_in[2];   // scalar int
    const int*   sample_idx = (const int*)d_in[3];   // (P,) int32

    float* out_v = (float*)d_out;                    // (B,P,3)
    float* out_f = out_v + (size_t)BB * PP * 3;      // (B,P,C)

    dim3 grid(BB * PP / 32), block(256);             // 256 blocks, 1 per CU
    pool_layer_kernel<<<grid, block, 0, stream>>>(
        vertices, feat, radius_p, sample_idx, out_v, out_f);
}